// Round 25
// baseline (238.320 us; speedup 1.0000x reference)
//
#include <hip/hip_runtime.h>
#include <hip/hip_bf16.h>

#define B_   4
#define DENC 512
#define T_   200
#define DDEC 640
#define U_   100
#define H_   640
#define V_   1025
#define VPAD 1152

typedef float f32x4 __attribute__((ext_vector_type(4)));
typedef _Float16 f16x8 __attribute__((ext_vector_type(8)));

// relu(e+d) on 8 packed fp16: 4x v_pk_add_f16 + 4x v_pk_max_f16
__device__ __forceinline__ uint4 addrelu16(uint4 e, uint4 d) {
    f16x8 ev = __builtin_bit_cast(f16x8, e);
    f16x8 dv = __builtin_bit_cast(f16x8, d);
    f16x8 s = ev + dv;
    f16x8 z = {(_Float16)0.f, (_Float16)0.f, (_Float16)0.f, (_Float16)0.f,
               (_Float16)0.f, (_Float16)0.f, (_Float16)0.f, (_Float16)0.f};
    s = __builtin_elementwise_max(s, z);
    return __builtin_bit_cast(uint4, s);
}

__device__ __forceinline__ void gload_lds16(const void* g, void* l) {
    __builtin_amdgcn_global_load_lds(
        (const __attribute__((address_space(1))) unsigned int*)g,
        (__attribute__((address_space(3))) unsigned int*)l, 16, 0, 0);
}

// ---------------- K1: fused prep (r23-proven): 512 thr / 8-way wave-split-d
// blocks [0,520): enc   [520,1040): dec   [1040,1220): wt
__global__ __launch_bounds__(512) void prep_fused_kernel(
    const float* __restrict__ enc, const float* __restrict__ W_enc,
    const float* __restrict__ b_enc,
    const float* __restrict__ dec, const float* __restrict__ W_pred,
    const float* __restrict__ b_pred,
    const float* __restrict__ W_out,
    _Float16* __restrict__ encP, _Float16* __restrict__ decP,
    _Float16* __restrict__ Wt)
{
    __shared__ float sbuf[8448];
    int bx = blockIdx.x;
    int tid = threadIdx.x;
    int lane = tid & 63, w = tid >> 6;

    if (bx < 520) {
        int b = bx / 130, r5 = bx % 130, hc = r5 / 13, tg = r5 % 13;
        int h  = hc * 64 + lane;
        int t0 = tg * 16;
        const float* Wc = W_enc + h;
        const float* ec = enc + (size_t)b * DENC * T_ + t0;
        int d0 = w * 64;
        float acc[16];
        #pragma unroll
        for (int i = 0; i < 16; ++i) acc[i] = 0.f;
        if (t0 + 16 <= T_) {
            #pragma unroll 8
            for (int i = 0; i < 64; ++i) {
                int d = d0 + i;
                float wv = Wc[(size_t)d * H_];
                const float* p = ec + (size_t)d * T_;
                float4 a0 = *(const float4*)(p);
                float4 a1 = *(const float4*)(p + 4);
                float4 a2 = *(const float4*)(p + 8);
                float4 a3 = *(const float4*)(p + 12);
                acc[0]+=wv*a0.x; acc[1]+=wv*a0.y; acc[2]+=wv*a0.z; acc[3]+=wv*a0.w;
                acc[4]+=wv*a1.x; acc[5]+=wv*a1.y; acc[6]+=wv*a1.z; acc[7]+=wv*a1.w;
                acc[8]+=wv*a2.x; acc[9]+=wv*a2.y; acc[10]+=wv*a2.z; acc[11]+=wv*a2.w;
                acc[12]+=wv*a3.x; acc[13]+=wv*a3.y; acc[14]+=wv*a3.z; acc[15]+=wv*a3.w;
            }
        } else {
            #pragma unroll 8
            for (int i = 0; i < 64; ++i) {
                int d = d0 + i;
                float wv = Wc[(size_t)d * H_];
                const float* p = ec + (size_t)d * T_;
                float4 a0 = *(const float4*)(p);
                float4 a1 = *(const float4*)(p + 4);
                acc[0]+=wv*a0.x; acc[1]+=wv*a0.y; acc[2]+=wv*a0.z; acc[3]+=wv*a0.w;
                acc[4]+=wv*a1.x; acc[5]+=wv*a1.y; acc[6]+=wv*a1.z; acc[7]+=wv*a1.w;
            }
        }
        #pragma unroll
        for (int t = 0; t < 16; ++t)
            sbuf[(w * 16 + t) * 66 + lane] = acc[t];
        __syncthreads();
        #pragma unroll
        for (int k = 0; k < 2; ++k) {
            int oi = tid + k * 512;
            int t = oi >> 6, hl = oi & 63;
            if (t0 + t < T_) {
                float s = 0.f;
                #pragma unroll
                for (int ww = 0; ww < 8; ++ww)
                    s += sbuf[(ww * 16 + t) * 66 + hl];
                s += b_enc[hc * 64 + hl];
                encP[((size_t)b * T_ + t0 + t) * H_ + hc * 64 + hl] = (_Float16)s;
            }
        }
    } else if (bx < 1040) {
        int i5 = bx - 520;
        int b = i5 / 130, r5 = i5 % 130, hc = r5 / 13, ug = r5 % 13;
        int h  = hc * 64 + lane;
        int u0 = ug * 8;
        const float* Wc = W_pred + h;
        const float* dc = dec + (size_t)b * DDEC * U_ + u0;
        int d0 = w * 80;
        float acc[8];
        #pragma unroll
        for (int i = 0; i < 8; ++i) acc[i] = 0.f;
        if (u0 + 8 <= U_) {
            #pragma unroll 8
            for (int i = 0; i < 80; ++i) {
                int d = d0 + i;
                float wv = Wc[(size_t)d * H_];
                const float* p = dc + (size_t)d * U_;
                float4 a0 = *(const float4*)(p);
                float4 a1 = *(const float4*)(p + 4);
                acc[0]+=wv*a0.x; acc[1]+=wv*a0.y; acc[2]+=wv*a0.z; acc[3]+=wv*a0.w;
                acc[4]+=wv*a1.x; acc[5]+=wv*a1.y; acc[6]+=wv*a1.z; acc[7]+=wv*a1.w;
            }
        } else {
            #pragma unroll 8
            for (int i = 0; i < 80; ++i) {
                int d = d0 + i;
                float wv = Wc[(size_t)d * H_];
                const float* p = dc + (size_t)d * U_;
                float4 a0 = *(const float4*)(p);
                acc[0]+=wv*a0.x; acc[1]+=wv*a0.y; acc[2]+=wv*a0.z; acc[3]+=wv*a0.w;
            }
        }
        #pragma unroll
        for (int u = 0; u < 8; ++u)
            sbuf[(w * 8 + u) * 66 + lane] = acc[u];
        __syncthreads();
        {
            int u = tid >> 6, hl = tid & 63;
            if (u0 + u < U_) {
                float s = 0.f;
                #pragma unroll
                for (int ww = 0; ww < 8; ++ww)
                    s += sbuf[(ww * 8 + u) * 66 + hl];
                s += b_pred[hc * 64 + hl];
                decP[((size_t)b * U_ + u0 + u) * H_ + hc * 64 + hl] = (_Float16)s;
            }
        }
    } else {
        int j = bx - 1040;
        int hc = j / 18, vc = j % 18;
        int h0 = hc * 64, v0 = vc * 64;
        float (*tile)[65] = (float(*)[65])sbuf;
        #pragma unroll
        for (int it = 0; it < 8; ++it) {
            int hl = it * 8 + (tid >> 6);
            int vl = tid & 63;
            int v = v0 + vl;
            tile[hl][vl] = (v < V_) ? W_out[(size_t)(h0 + hl) * V_ + v] : 0.f;
        }
        __syncthreads();
        #pragma unroll
        for (int it = 0; it < 8; ++it) {
            int vl = it * 8 + (tid >> 6);
            int hl = tid & 63;
            Wt[(size_t)(v0 + vl) * H_ + h0 + hl] = (_Float16)tile[hl][vl];
        }
    }
}

// ---------------- K4: 128x256 geometry — same per-wave step as r23, half the
// barrier events per output, 3 blocks/CU x 8 waves = 24 waves/CU.
// 512 thr = 8 waves (2 wr x 4 wc); wave = 64x64, acc[4][4]; BK=32, 20 steps.
// LDS single 48KB block: LA [2][128][4]u4 @0, LB [2][256][4]u4 @16KB; epilogue
// etile [2][16][260] f32 (33KB) aliases it.
// blocks [0,2704): GEMM (XCD swizzle, 2704=8*338). [2704,2861): v=1024 col.
__global__ __launch_bounds__(512, 4) void joint_kernel(
    const unsigned short* __restrict__ encP,   // [B,T,H] fp16
    const unsigned short* __restrict__ decP,   // [B,U,H] fp16
    const unsigned short* __restrict__ Wt,     // [VPAD][H] fp16
    const float* __restrict__ b_out,           // [V]
    float* __restrict__ out)                   // [B,T,U,V] f32
{
    __shared__ uint4 LDSu[3072];               // 48 KB
    uint4* LA = LDSu;                          // [2][128][4]
    uint4* LB = LDSu + 1024;                   // [2][256][4]
    int tid = threadIdx.x;

    if (blockIdx.x >= 2704) {
        // ---- fused lastcol: v = 1024 (512-thread blocks)
        int idx = (blockIdx.x - 2704) * 512 + tid;
        if (idx >= B_ * T_ * U_) return;
        int u = idx % U_;
        int t = (idx / U_) % T_;
        int b = idx / (U_ * T_);
        const uint4* e = (const uint4*)(encP + ((size_t)b * T_ + t) * H_);
        const uint4* d = (const uint4*)(decP + ((size_t)b * U_ + u) * H_);
        const uint4* wv = (const uint4*)(Wt + (size_t)1024 * H_);
        float acc1 = 0.f;
        for (int c = 0; c < H_ / 8; ++c) {
            f16x8 x = __builtin_bit_cast(f16x8, addrelu16(e[c], d[c]));
            f16x8 wq = __builtin_bit_cast(f16x8, wv[c]);
            #pragma unroll
            for (int m = 0; m < 8; ++m)
                acc1 += (float)x[m] * (float)wq[m];
        }
        out[((size_t)(b * T_ + t) * U_ + u) * V_ + 1024] = acc1 + b_out[1024];
        return;
    }

    // ---- XCD swizzle: f -> n = (f&7)*338 + (f>>3); n = vi*676 + b*169 + tu
    int f   = blockIdx.x;
    int n   = (f & 7) * 338 + (f >> 3);
    int vi  = n / 676;
    int rem = n - vi * 676;
    int b   = rem / 169;
    int tu  = rem - b * 169;
    int tt = tu / 13, ut = tu % 13;
    int t0 = tt * 16, u0 = ut * 8, vb = vi * 256;   // 13 t-tiles of 16 (t padded)
    int lane = tid & 63, w = tid >> 6;
    int wr = w >> 2, wc = w & 3;                    // 2x4 wave grid
    int lrow = lane & 15, kg = lane >> 4;

    // ---- A-build: thread owns row r (0..127), chunk kc (0..3) — 1 task/thread
    int r  = tid >> 2, kc = tid & 3;
    int ta = t0 + (r >> 3); if (ta > T_ - 1) ta = T_ - 1;
    int ua = u0 + (r & 7);  if (ua > U_ - 1) ua = U_ - 1;
    const unsigned short* eR = encP + ((size_t)b * T_ + ta) * H_ + kc * 8;
    const unsigned short* dR = decP + ((size_t)b * U_ + ua) * H_ + kc * 8;
    int fA = (r >> 1) & 3;

    // ---- B gload: wave w stages local cols 32w..32w+31 (2 instrs of 16 cols)
    int pcB = lane & 3;
    const unsigned short* gB[2];
    #pragma unroll
    for (int m = 0; m < 2; ++m) {
        int cl = w * 32 + m * 16 + (lane >> 2);
        gB[m] = Wt + (size_t)(vb + cl) * H_ + (pcB ^ ((cl >> 1) & 3)) * 8;
    }

    f32x4 acc[4][4];
    #pragma unroll
    for (int i = 0; i < 4; ++i)
        #pragma unroll
        for (int j = 0; j < 4; ++j)
            acc[i][j] = (f32x4){0.f, 0.f, 0.f, 0.f};

    // ---- prologue: stage k-step 0 into buf 0
    {
        uint4 E = *(const uint4*)(eR);
        uint4 D = *(const uint4*)(dR);
        LA[(0 * 128 + r) * 4 + (kc ^ fA)] = addrelu16(E, D);
        #pragma unroll
        for (int m = 0; m < 2; ++m)
            gload_lds16(gB[m], &LB[(size_t)(0 * 256 + w * 32 + m * 16) * 4]);
    }
    __syncthreads();

    // ---- main K loop: 20 steps of K=32
    #pragma unroll 2
    for (int kt = 0; kt < 20; ++kt) {
        int cur = kt & 1;
        uint4 En, Dn;
        if (kt < 19) {
            En = *(const uint4*)(eR + (kt + 1) * 32);
            Dn = *(const uint4*)(dR + (kt + 1) * 32);
            #pragma unroll
            for (int m = 0; m < 2; ++m)
                gload_lds16(gB[m] + (kt + 1) * 32,
                            &LB[(size_t)((cur ^ 1) * 256 + w * 32 + m * 16) * 4]);
        }
        f16x8 a[4], bq[4];
        #pragma unroll
        for (int i = 0; i < 4; ++i) {
            int row = wr * 64 + i * 16 + lrow;
            a[i] = __builtin_bit_cast(f16x8, LA[(cur * 128 + row) * 4 + (kg ^ ((row >> 1) & 3))]);
        }
        #pragma unroll
        for (int j = 0; j < 4; ++j) {
            int col = wc * 64 + j * 16 + lrow;
            bq[j] = __builtin_bit_cast(f16x8, LB[(cur * 256 + col) * 4 + (kg ^ ((col >> 1) & 3))]);
        }
        #pragma unroll
        for (int i = 0; i < 4; ++i)
            #pragma unroll
            for (int j = 0; j < 4; ++j)
                acc[i][j] = __builtin_amdgcn_mfma_f32_16x16x32_f16(a[i], bq[j], acc[i][j], 0, 0, 0);
        if (kt < 19)
            LA[((cur ^ 1) * 128 + r) * 4 + (kc ^ fA)] = addrelu16(En, Dn);
        __syncthreads();
    }

    // ---- epilogue: acc -> etile [2][16][260] f32 -> 256B-contiguous scalar stores
    float* etile = (float*)LDSu;
    #pragma unroll
    for (int i = 0; i < 4; ++i) {
        __syncthreads();
        #pragma unroll
        for (int j = 0; j < 4; ++j) {
            int col = wc * 64 + j * 16 + lrow;
            float bo = b_out[vb + col];
            #pragma unroll
            for (int q = 0; q < 4; ++q)
                etile[(wr * 16 + kg * 4 + q) * 260 + col] = acc[i][j][q] + bo;
        }
        __syncthreads();
        // 32 rows (2 wr-groups x 16); wave w stores 4: wrs=w>>2, r16=(w&3)*4+rr
        #pragma unroll
        for (int rr = 0; rr < 4; ++rr) {
            int wrs = w >> 2;
            int r16 = (w & 3) * 4 + rr;
            int row = wrs * 64 + i * 16 + r16;
            int t = t0 + (row >> 3);
            int u = u0 + (row & 7);
            if (t < T_ && u < U_) {
                float* ob = &out[(((size_t)b * T_ + t) * U_ + u) * V_ + vb];
                const float* lb = &etile[(wrs * 16 + r16) * 260];
                #pragma unroll
                for (int it = 0; it < 4; ++it)
                    ob[it * 64 + lane] = lb[it * 64 + lane];
            }
        }
    }
}

extern "C" void kernel_launch(void* const* d_in, const int* in_sizes, int n_in,
                              void* d_out, int out_size, void* d_ws, size_t ws_size,
                              hipStream_t stream) {
    const float* enc    = (const float*)d_in[0];
    const float* dec    = (const float*)d_in[1];
    const float* W_enc  = (const float*)d_in[2];
    const float* b_enc  = (const float*)d_in[3];
    const float* W_pred = (const float*)d_in[4];
    const float* b_pred = (const float*)d_in[5];
    const float* W_out  = (const float*)d_in[6];
    const float* b_out  = (const float*)d_in[7];
    float* out = (float*)d_out;

    // fp16 buffers: encP 512,000 elems = 1,024,000 B
    char* ws = (char*)d_ws;
    _Float16* encP = (_Float16*)ws;                        // 1,024,000 B
    _Float16* decP = (_Float16*)(ws + 1024000);            //   512,000 B
    _Float16* Wt   = (_Float16*)(ws + 1024000 + 512000);   // 1,474,560 B

    prep_fused_kernel<<<dim3(1220), 512, 0, stream>>>(
        enc, W_enc, b_enc, dec, W_pred, b_pred, W_out, encP, decP, Wt);
    joint_kernel<<<dim3(2704 + 157), 512, 0, stream>>>(
        (const unsigned short*)encP, (const unsigned short*)decP,
        (const unsigned short*)Wt, b_out, out);
}

// Round 26
// 236.147 us; speedup vs baseline: 1.0092x; 1.0092x over previous
//
#include <hip/hip_runtime.h>
#include <hip/hip_bf16.h>

#define B_   4
#define DENC 512
#define T_   200
#define DDEC 640
#define U_   100
#define H_   640
#define V_   1025
#define VPAD 1152

typedef float f32x4 __attribute__((ext_vector_type(4)));
typedef _Float16 f16x8 __attribute__((ext_vector_type(8)));

// relu(e+d) on 8 packed fp16: 4x v_pk_add_f16 + 4x v_pk_max_f16
__device__ __forceinline__ uint4 addrelu16(uint4 e, uint4 d) {
    f16x8 ev = __builtin_bit_cast(f16x8, e);
    f16x8 dv = __builtin_bit_cast(f16x8, d);
    f16x8 s = ev + dv;
    f16x8 z = {(_Float16)0.f, (_Float16)0.f, (_Float16)0.f, (_Float16)0.f,
               (_Float16)0.f, (_Float16)0.f, (_Float16)0.f, (_Float16)0.f};
    s = __builtin_elementwise_max(s, z);
    return __builtin_bit_cast(uint4, s);
}

__device__ __forceinline__ void gload_lds16(const void* g, void* l) {
    __builtin_amdgcn_global_load_lds(
        (const __attribute__((address_space(1))) unsigned int*)g,
        (__attribute__((address_space(3))) unsigned int*)l, 16, 0, 0);
}

// ---------------- K1: fused prep (r23-proven): 512 thr / 8-way wave-split-d
// blocks [0,520): enc   [520,1040): dec   [1040,1220): wt
__global__ __launch_bounds__(512) void prep_fused_kernel(
    const float* __restrict__ enc, const float* __restrict__ W_enc,
    const float* __restrict__ b_enc,
    const float* __restrict__ dec, const float* __restrict__ W_pred,
    const float* __restrict__ b_pred,
    const float* __restrict__ W_out,
    _Float16* __restrict__ encP, _Float16* __restrict__ decP,
    _Float16* __restrict__ Wt)
{
    __shared__ float sbuf[8448];
    int bx = blockIdx.x;
    int tid = threadIdx.x;
    int lane = tid & 63, w = tid >> 6;

    if (bx < 520) {
        int b = bx / 130, r5 = bx % 130, hc = r5 / 13, tg = r5 % 13;
        int h  = hc * 64 + lane;
        int t0 = tg * 16;
        const float* Wc = W_enc + h;
        const float* ec = enc + (size_t)b * DENC * T_ + t0;
        int d0 = w * 64;
        float acc[16];
        #pragma unroll
        for (int i = 0; i < 16; ++i) acc[i] = 0.f;
        if (t0 + 16 <= T_) {
            #pragma unroll 8
            for (int i = 0; i < 64; ++i) {
                int d = d0 + i;
                float wv = Wc[(size_t)d * H_];
                const float* p = ec + (size_t)d * T_;
                float4 a0 = *(const float4*)(p);
                float4 a1 = *(const float4*)(p + 4);
                float4 a2 = *(const float4*)(p + 8);
                float4 a3 = *(const float4*)(p + 12);
                acc[0]+=wv*a0.x; acc[1]+=wv*a0.y; acc[2]+=wv*a0.z; acc[3]+=wv*a0.w;
                acc[4]+=wv*a1.x; acc[5]+=wv*a1.y; acc[6]+=wv*a1.z; acc[7]+=wv*a1.w;
                acc[8]+=wv*a2.x; acc[9]+=wv*a2.y; acc[10]+=wv*a2.z; acc[11]+=wv*a2.w;
                acc[12]+=wv*a3.x; acc[13]+=wv*a3.y; acc[14]+=wv*a3.z; acc[15]+=wv*a3.w;
            }
        } else {
            #pragma unroll 8
            for (int i = 0; i < 64; ++i) {
                int d = d0 + i;
                float wv = Wc[(size_t)d * H_];
                const float* p = ec + (size_t)d * T_;
                float4 a0 = *(const float4*)(p);
                float4 a1 = *(const float4*)(p + 4);
                acc[0]+=wv*a0.x; acc[1]+=wv*a0.y; acc[2]+=wv*a0.z; acc[3]+=wv*a0.w;
                acc[4]+=wv*a1.x; acc[5]+=wv*a1.y; acc[6]+=wv*a1.z; acc[7]+=wv*a1.w;
            }
        }
        #pragma unroll
        for (int t = 0; t < 16; ++t)
            sbuf[(w * 16 + t) * 66 + lane] = acc[t];
        __syncthreads();
        #pragma unroll
        for (int k = 0; k < 2; ++k) {
            int oi = tid + k * 512;
            int t = oi >> 6, hl = oi & 63;
            if (t0 + t < T_) {
                float s = 0.f;
                #pragma unroll
                for (int ww = 0; ww < 8; ++ww)
                    s += sbuf[(ww * 16 + t) * 66 + hl];
                s += b_enc[hc * 64 + hl];
                encP[((size_t)b * T_ + t0 + t) * H_ + hc * 64 + hl] = (_Float16)s;
            }
        }
    } else if (bx < 1040) {
        int i5 = bx - 520;
        int b = i5 / 130, r5 = i5 % 130, hc = r5 / 13, ug = r5 % 13;
        int h  = hc * 64 + lane;
        int u0 = ug * 8;
        const float* Wc = W_pred + h;
        const float* dc = dec + (size_t)b * DDEC * U_ + u0;
        int d0 = w * 80;
        float acc[8];
        #pragma unroll
        for (int i = 0; i < 8; ++i) acc[i] = 0.f;
        if (u0 + 8 <= U_) {
            #pragma unroll 8
            for (int i = 0; i < 80; ++i) {
                int d = d0 + i;
                float wv = Wc[(size_t)d * H_];
                const float* p = dc + (size_t)d * U_;
                float4 a0 = *(const float4*)(p);
                float4 a1 = *(const float4*)(p + 4);
                acc[0]+=wv*a0.x; acc[1]+=wv*a0.y; acc[2]+=wv*a0.z; acc[3]+=wv*a0.w;
                acc[4]+=wv*a1.x; acc[5]+=wv*a1.y; acc[6]+=wv*a1.z; acc[7]+=wv*a1.w;
            }
        } else {
            #pragma unroll 8
            for (int i = 0; i < 80; ++i) {
                int d = d0 + i;
                float wv = Wc[(size_t)d * H_];
                const float* p = dc + (size_t)d * U_;
                float4 a0 = *(const float4*)(p);
                acc[0]+=wv*a0.x; acc[1]+=wv*a0.y; acc[2]+=wv*a0.z; acc[3]+=wv*a0.w;
            }
        }
        #pragma unroll
        for (int u = 0; u < 8; ++u)
            sbuf[(w * 8 + u) * 66 + lane] = acc[u];
        __syncthreads();
        {
            int u = tid >> 6, hl = tid & 63;
            if (u0 + u < U_) {
                float s = 0.f;
                #pragma unroll
                for (int ww = 0; ww < 8; ++ww)
                    s += sbuf[(ww * 8 + u) * 66 + hl];
                s += b_pred[hc * 64 + hl];
                decP[((size_t)b * U_ + u0 + u) * H_ + hc * 64 + hl] = (_Float16)s;
            }
        }
    } else {
        int j = bx - 1040;
        int hc = j / 18, vc = j % 18;
        int h0 = hc * 64, v0 = vc * 64;
        float (*tile)[65] = (float(*)[65])sbuf;
        #pragma unroll
        for (int it = 0; it < 8; ++it) {
            int hl = it * 8 + (tid >> 6);
            int vl = tid & 63;
            int v = v0 + vl;
            tile[hl][vl] = (v < V_) ? W_out[(size_t)(h0 + hl) * V_ + v] : 0.f;
        }
        __syncthreads();
        #pragma unroll
        for (int it = 0; it < 8; ++it) {
            int vl = it * 8 + (tid >> 6);
            int hl = tid & 63;
            Wt[(size_t)(v0 + vl) * H_ + h0 + hl] = (_Float16)tile[hl][vl];
        }
    }
}

// ---------------- K4: r23 champion joint: r8 2-phase skeleton, fp16 operands,
// LDS-transpose epilogue (256B-contiguous scalar stores), XCD swizzle,
// __launch_bounds__(256,4) occupancy hint (4 blocks/CU).
// blocks [0,5200): GEMM tiles.  blocks [5200,5513): v=1024 column.
#define ESTR 260
__global__ __launch_bounds__(256, 4) void joint_kernel(
    const unsigned short* __restrict__ encP,   // [B,T,H] fp16
    const unsigned short* __restrict__ decP,   // [B,U,H] fp16
    const unsigned short* __restrict__ Wt,     // [VPAD][H] fp16
    const float* __restrict__ b_out,           // [V]
    float* __restrict__ out)                   // [B,T,U,V] f32
{
    __shared__ uint4 LA[2][64][4];             // 8 KB
    __shared__ uint4 LB[2][256][4];            // 32 KB
    int tid = threadIdx.x;

    if (blockIdx.x >= 5200) {
        int idx = (blockIdx.x - 5200) * 256 + tid;
        if (idx >= B_ * T_ * U_) return;
        int u = idx % U_;
        int t = (idx / U_) % T_;
        int b = idx / (U_ * T_);
        const uint4* e = (const uint4*)(encP + ((size_t)b * T_ + t) * H_);
        const uint4* d = (const uint4*)(decP + ((size_t)b * U_ + u) * H_);
        const uint4* wv = (const uint4*)(Wt + (size_t)1024 * H_);
        float acc1 = 0.f;
        for (int c = 0; c < H_ / 8; ++c) {
            f16x8 x = __builtin_bit_cast(f16x8, addrelu16(e[c], d[c]));
            f16x8 wq = __builtin_bit_cast(f16x8, wv[c]);
            #pragma unroll
            for (int m = 0; m < 8; ++m)
                acc1 += (float)x[m] * (float)wq[m];
        }
        out[((size_t)(b * T_ + t) * U_ + u) * V_ + 1024] = acc1 + b_out[1024];
        return;
    }

    int f   = blockIdx.x;
    int n   = (f & 7) * 650 + (f >> 3);
    int vi  = n / 1300;
    int rem = n - vi * 1300;
    int b   = rem / 325;
    int tu  = rem - b * 325;

    int tt = tu / 13, ut = tu % 13;
    int t0 = tt * 8, u0 = ut * 8, vb = vi * 256;
    int lane = tid & 63, w = tid >> 6;
    int lrow = lane & 15, kg = lane >> 4;

    int r  = tid >> 2, kc = tid & 3;
    int ta = t0 + (r >> 3);
    int ua = u0 + (r & 7); if (ua > U_ - 1) ua = U_ - 1;
    const unsigned short* eR = encP + ((size_t)b * T_ + ta) * H_ + kc * 8;
    const unsigned short* dR = decP + ((size_t)b * U_ + ua) * H_ + kc * 8;
    int fA = (r >> 1) & 3;

    int pcB = lane & 3;
    const unsigned short* gB[4];
    #pragma unroll
    for (int m = 0; m < 4; ++m) {
        int cl = w * 64 + m * 16 + (lane >> 2);
        gB[m] = Wt + (size_t)(vb + cl) * H_ + (pcB ^ ((cl >> 1) & 3)) * 8;
    }

    f32x4 acc[4][4];
    #pragma unroll
    for (int i = 0; i < 4; ++i)
        #pragma unroll
        for (int j = 0; j < 4; ++j)
            acc[i][j] = (f32x4){0.f, 0.f, 0.f, 0.f};

    {
        uint4 E = *(const uint4*)(eR);
        uint4 D = *(const uint4*)(dR);
        LA[0][r][kc ^ fA] = addrelu16(E, D);
        #pragma unroll
        for (int m = 0; m < 4; ++m)
            gload_lds16(gB[m], &LB[0][w * 64 + m * 16][0]);
    }
    __syncthreads();

    #pragma unroll 2
    for (int kt = 0; kt < 20; ++kt) {
        int cur = kt & 1;
        uint4 En, Dn;
        if (kt < 19) {
            En = *(const uint4*)(eR + (kt + 1) * 32);
            Dn = *(const uint4*)(dR + (kt + 1) * 32);
            #pragma unroll
            for (int m = 0; m < 4; ++m)
                gload_lds16(gB[m] + (kt + 1) * 32, &LB[cur ^ 1][w * 64 + m * 16][0]);
        }
        f16x8 a[4], bq[4];
        #pragma unroll
        for (int i = 0; i < 4; ++i) {
            int row = i * 16 + lrow;
            a[i] = __builtin_bit_cast(f16x8, LA[cur][row][kg ^ ((row >> 1) & 3)]);
        }
        #pragma unroll
        for (int j = 0; j < 4; ++j) {
            int col = w * 64 + j * 16 + lrow;
            bq[j] = __builtin_bit_cast(f16x8, LB[cur][col][kg ^ ((col >> 1) & 3)]);
        }
        #pragma unroll
        for (int i = 0; i < 4; ++i)
            #pragma unroll
            for (int j = 0; j < 4; ++j)
                acc[i][j] = __builtin_amdgcn_mfma_f32_16x16x32_f16(a[i], bq[j], acc[i][j], 0, 0, 0);
        if (kt < 19)
            LA[cur ^ 1][r][kc ^ fA] = addrelu16(En, Dn);
        __syncthreads();
    }

    float* etile = (float*)LB;
    #pragma unroll
    for (int i = 0; i < 4; ++i) {
        __syncthreads();
        #pragma unroll
        for (int j = 0; j < 4; ++j) {
            int col = w * 64 + j * 16 + lrow;
            float bo = b_out[vb + col];
            #pragma unroll
            for (int q = 0; q < 4; ++q)
                etile[(kg * 4 + q) * ESTR + col] = acc[i][j][q] + bo;
        }
        __syncthreads();
        #pragma unroll
        for (int rr = 0; rr < 4; ++rr) {
            int row16 = w * 4 + rr;
            int row = i * 16 + row16;
            int t = t0 + (row >> 3);
            int u = u0 + (row & 7);
            if (u < U_) {
                float* ob = &out[(((size_t)b * T_ + t) * U_ + u) * V_ + vb];
                const float* lb = &etile[row16 * ESTR];
                #pragma unroll
                for (int it = 0; it < 4; ++it)
                    ob[it * 64 + lane] = lb[it * 64 + lane];
            }
        }
    }
}

extern "C" void kernel_launch(void* const* d_in, const int* in_sizes, int n_in,
                              void* d_out, int out_size, void* d_ws, size_t ws_size,
                              hipStream_t stream) {
    const float* enc    = (const float*)d_in[0];
    const float* dec    = (const float*)d_in[1];
    const float* W_enc  = (const float*)d_in[2];
    const float* b_enc  = (const float*)d_in[3];
    const float* W_pred = (const float*)d_in[4];
    const float* b_pred = (const float*)d_in[5];
    const float* W_out  = (const float*)d_in[6];
    const float* b_out  = (const float*)d_in[7];
    float* out = (float*)d_out;

    // fp16 buffers: encP 512,000 elems = 1,024,000 B
    char* ws = (char*)d_ws;
    _Float16* encP = (_Float16*)ws;                        // 1,024,000 B
    _Float16* decP = (_Float16*)(ws + 1024000);            //   512,000 B
    _Float16* Wt   = (_Float16*)(ws + 1024000 + 512000);   // 1,474,560 B

    prep_fused_kernel<<<dim3(1220), 512, 0, stream>>>(
        enc, W_enc, b_enc, dec, W_pred, b_pred, W_out, encP, decP, Wt);
    joint_kernel<<<dim3(5200 + (B_ * T_ * U_ + 255) / 256), 256, 0, stream>>>(
        (const unsigned short*)encP, (const unsigned short*)decP,
        (const unsigned short*)Wt, b_out, out);
}